// Round 16
// baseline (248.452 us; speedup 1.0000x reference)
//
#include <hip/hip_runtime.h>
#include <hip/hip_bf16.h>
#include <cstdint>

typedef __attribute__((ext_vector_type(8))) short bf16x8;
typedef __attribute__((ext_vector_type(4))) float f32x4;

#define BN_EPS 1e-5f

__device__ __forceinline__ unsigned short f2bf(float f) {
    unsigned int u = __float_as_uint(f);
    unsigned int r = (u + 0x7FFFu + ((u >> 16) & 1u)) >> 16;
    return (unsigned short)r;
}
__device__ __forceinline__ float bf2f(unsigned short h) {
    return __uint_as_float(((unsigned int)h) << 16);
}
// monotone float -> uint map (order-preserving), for atomicMax-based float max
__device__ __forceinline__ unsigned int encf(float f) {
    unsigned int u = __float_as_uint(f);
    return (u & 0x80000000u) ? ~u : (u | 0x80000000u);
}
__device__ __forceinline__ float decf(unsigned int e) {
    return __uint_as_float((e & 0x80000000u) ? (e & 0x7FFFFFFFu) : ~e);
}

__device__ __forceinline__ long long lbound(const int* __restrict__ b, long long n, int key) {
    long long lo = 0, hi = n;
    while (lo < hi) { long long mid = (lo + hi) >> 1; if (b[mid] < key) lo = mid + 1; else hi = mid; }
    return lo;
}

__device__ __forceinline__ void gl_lds16(const unsigned short* g, unsigned short* l) {
    __builtin_amdgcn_global_load_lds((const __attribute__((address_space(1))) unsigned int*)g,
                                     (__attribute__((address_space(3))) unsigned int*)l,
                                     16, 0, 0);
}

// ---- fold: BN-fold, W1 interleave, W23 -> bf16 hi/lo B-frags, W4 -> bf16 B-frags, out init ----
__global__ void fold_kernel(const float* __restrict__ W1, const float* __restrict__ b1,
                            const float* __restrict__ g1, const float* __restrict__ be1,
                            const float* __restrict__ m1, const float* __restrict__ v1,
                            const float* __restrict__ W2, const float* __restrict__ b2,
                            const float* __restrict__ W3, const float* __restrict__ b3,
                            const float* __restrict__ g3, const float* __restrict__ be3,
                            const float* __restrict__ m3, const float* __restrict__ v3,
                            const float* __restrict__ W4,
                            unsigned short* __restrict__ W4p,
                            unsigned short* __restrict__ W23ph, unsigned short* __restrict__ W23pl,
                            float* __restrict__ W1c, float* __restrict__ b23,
                            unsigned int* __restrict__ out, int out_size) {
    int tid = blockIdx.x * blockDim.x + threadIdx.x; // 131072 threads
    if (tid < 131072) {
        // W4p flat = ((nt*4+kf)*64 + lane)*8 + j ; element = W4[k][col]
        int j = tid & 7, lane = (tid >> 3) & 63, kf = (tid >> 9) & 3, nt = tid >> 11;
        int col = nt * 16 + (lane & 15);
        int k = kf * 32 + (lane >> 4) * 8 + j;
        W4p[tid] = f2bf(W4[k * 1024 + col]);
    }
    // out init to encf(-inf)
    if (tid < out_size) out[tid] = 0x007FFFFFu;
    if (tid + 131072 < out_size) out[tid + 131072] = 0x007FFFFFu;
    if (tid < 8192) { // W23 (incl. s3) -> B-frag hi/lo: flat = ((nn*2+kf)*64+lane)*8+j
        int j = tid & 7, lane = (tid >> 3) & 63, kf = (tid >> 9) & 1, nn = tid >> 10;
        int col = nn * 16 + (lane & 15);
        int k = kf * 32 + (lane >> 4) * 8 + j;
        float s3 = g3[col] / sqrtf(v3[col] + BN_EPS);
        float acc = 0.f;
        for (int o = 0; o < 64; ++o) acc += W2[k * 64 + o] * W3[o * 128 + col];
        float w = acc * s3;
        unsigned short hi = f2bf(w);
        W23ph[tid] = hi;
        W23pl[tid] = f2bf(w - bf2f(hi));
    }
    if (tid < 128) { // b23[j] = (sum_o b2[o]W3[o][j] + b3[j] - m3[j])*s3[j] + be3[j]
        float s3 = g3[tid] / sqrtf(v3[tid] + BN_EPS);
        float acc = b3[tid] - m3[tid];
        for (int o = 0; o < 64; ++o) acc += b2[o] * W3[o * 128 + tid];
        b23[tid] = acc * s3 + be3[tid];
    }
    if (tid < 256) { // W1c[o][c] = {W1 rows * s1, folded bias}
        int o = tid >> 2, c = tid & 3;
        float s1 = g1[o] / sqrtf(v1[o] + BN_EPS);
        W1c[tid] = (c < 3) ? W1[c * 64 + o] * s1 : (b1[o] - m1[o]) * s1 + be1[o];
    }
}

// ---- fused: R14 body + per-wave gl_lds B-ring (3x4KB, counted vmcnt, store-free loop) ----
__global__ __launch_bounds__(128, 4) void fused_kernel(const float* __restrict__ x,
                                                       const float* __restrict__ W1c,
                                                       const unsigned short* __restrict__ W23ph,
                                                       const unsigned short* __restrict__ W23pl,
                                                       const float* __restrict__ b23,
                                                       const unsigned short* __restrict__ W4p,
                                                       const float* __restrict__ b4,
                                                       const int* __restrict__ batch,
                                                       unsigned int* __restrict__ out,
                                                       float* __restrict__ tilemax,
                                                       int* __restrict__ gtile,
                                                       long long pbase, int ntiles, long long Ntot) {
    // per-wave 16KB slice: bytes [0,12288) = MLP h3 (first 9216) / gemm B-ring (3 x 4096);
    //                      bytes [12288,16384) = per-tile col-max accumulator (1024 floats)
    __shared__ unsigned short ldss[2][8192];
    int wave = blockIdx.x * 2 + (threadIdx.x >> 6);
    if (wave >= ntiles) return;                  // wave-level exit; no barriers below
    unsigned short* h3 = ldss[threadIdx.x >> 6];
    int lane = threadIdx.x & 63;
    int q = lane >> 4, r16 = lane & 15;
    long long p0 = pbase + (long long)wave * 64;

    // ---- layer 1 (3->64): lane computes h1[16mt+r16][32kf+8q+j] = its layer-2 A-frag elements ----
    float xv[4][3];
    bool valid[4];
#pragma unroll
    for (int mt = 0; mt < 4; ++mt) {
        long long p = p0 + mt * 16 + r16;
        if (p < Ntot) {
            xv[mt][0] = x[p * 3 + 0]; xv[mt][1] = x[p * 3 + 1]; xv[mt][2] = x[p * 3 + 2];
            valid[mt] = true;
        } else {
            xv[mt][0] = xv[mt][1] = xv[mt][2] = 0.f; valid[mt] = false;
        }
    }
    bf16x8 a2[4][2];
#pragma unroll
    for (int kf = 0; kf < 2; ++kf)
#pragma unroll
        for (int j = 0; j < 8; ++j) {
            int f = kf * 32 + q * 8 + j;
            float4 w = *reinterpret_cast<const float4*>(W1c + f * 4);
#pragma unroll
            for (int mt = 0; mt < 4; ++mt) {
                float v = fmaf(xv[mt][0], w.x, fmaf(xv[mt][1], w.y, fmaf(xv[mt][2], w.z, w.w)));
                v = valid[mt] ? fmaxf(v, 0.f) : 0.f;
                a2[mt][kf][j] = (short)f2bf(v);
            }
        }

    // ---- layer 2+3 (64->128) via MFMA in two halves; each half: LDS round-trip -> A-frags ----
    bf16x8 a[4][4];
#pragma unroll
    for (int half = 0; half < 2; ++half) {
#pragma unroll
        for (int n = 0; n < 4; ++n) {
            int nn = half * 4 + n;
            f32x4 acc2[4];
#pragma unroll
            for (int mt = 0; mt < 4; ++mt) acc2[mt] = (f32x4){0.f, 0.f, 0.f, 0.f};
#pragma unroll
            for (int kf = 0; kf < 2; ++kf) {
                bf16x8 bh = *reinterpret_cast<const bf16x8*>(W23ph + (size_t)((nn * 2 + kf) * 64 + lane) * 8);
                bf16x8 bl = *reinterpret_cast<const bf16x8*>(W23pl + (size_t)((nn * 2 + kf) * 64 + lane) * 8);
#pragma unroll
                for (int mt = 0; mt < 4; ++mt) {
                    acc2[mt] = __builtin_amdgcn_mfma_f32_16x16x32_bf16(a2[mt][kf], bh, acc2[mt], 0, 0, 0);
                    acc2[mt] = __builtin_amdgcn_mfma_f32_16x16x32_bf16(a2[mt][kf], bl, acc2[mt], 0, 0, 0);
                }
            }
            int col = nn * 16 + r16;
            float bias = b23[col];
#pragma unroll
            for (int mt = 0; mt < 4; ++mt)
#pragma unroll
                for (int r = 0; r < 4; ++r) {
                    int row = mt * 16 + q * 4 + r;   // C-layout: row=(lane>>4)*4+reg
                    float v = fmaxf(acc2[mt][r] + bias, 0.f);
                    h3[row * 72 + n * 16 + r16] = f2bf(v);
                }
        }
        asm volatile("s_waitcnt lgkmcnt(0)" ::: "memory");
        // read this half's A-frags: a[mt][half*2+kfl][j] = h3half[16mt+r16][kfl*32+q*8+j]
#pragma unroll
        for (int mt = 0; mt < 4; ++mt)
#pragma unroll
            for (int kfl = 0; kfl < 2; ++kfl)
                a[mt][half * 2 + kfl] =
                    *reinterpret_cast<const bf16x8*>(h3 + (16 * mt + r16) * 72 + kfl * 32 + q * 8);
        asm volatile("s_waitcnt lgkmcnt(0)" ::: "memory");
    }

    long long plast = p0 + 63; if (plast > Ntot - 1) plast = Ntot - 1;
    int gfirst = batch[(p0 < Ntot) ? p0 : (Ntot - 1)];
    int glast = batch[plast];
    bool fast = (gfirst == glast) && (p0 + 63 < Ntot);
    if (lane == 0) gtile[wave] = fast ? gfirst : -1;

    if (fast) {
        float* tmlds = (float*)(h3 + 6144);      // 1024 floats, per-wave
        // prologue: stage nt = 0,1,2 into ring buffers 0,1,2 (12 gl_lds in flight)
#pragma unroll
        for (int t = 0; t < 3; ++t)
#pragma unroll
            for (int kf = 0; kf < 4; ++kf)
                gl_lds16(W4p + (size_t)((t * 4 + kf) * 512) + lane * 8,
                         h3 + t * 2048 + kf * 512);
        // lane's B-frag byte address within a ring buffer (buffer s at +s*4096)
        unsigned lbase = (unsigned)(size_t)(__attribute__((address_space(3))) unsigned short*)h3;
        unsigned laddr0 = lbase + (unsigned)lane * 16u;

        int s = 0;
        for (int g8 = 0; g8 < 8; ++g8) {
            float m8[8];
#pragma unroll
            for (int i8 = 0; i8 < 8; ++i8) {
                int nt = g8 * 8 + i8;
                // wait until only the 8 newer loads remain -> this buffer's 4 are complete;
                // then read B-frags + drain lgkm inside ONE asm (compiler sees pure data dep)
                unsigned ad = laddr0 + (unsigned)s * 4096u;
                bf16x8 b0, b1, b2, b3;
                asm volatile("s_waitcnt vmcnt(8)\n\t"
                             "ds_read_b128 %0, %4 offset:0\n\t"
                             "ds_read_b128 %1, %4 offset:1024\n\t"
                             "ds_read_b128 %2, %4 offset:2048\n\t"
                             "ds_read_b128 %3, %4 offset:3072\n\t"
                             "s_waitcnt lgkmcnt(0)"
                             : "=&v"(b0), "=&v"(b1), "=&v"(b2), "=&v"(b3)
                             : "v"(ad) : "memory");
                f32x4 acc[4];
#pragma unroll
                for (int mt = 0; mt < 4; ++mt) acc[mt] = (f32x4){0.f, 0.f, 0.f, 0.f};
#pragma unroll
                for (int mt = 0; mt < 4; ++mt) {
                    acc[mt] = __builtin_amdgcn_mfma_f32_16x16x32_bf16(a[mt][0], b0, acc[mt], 0, 0, 0);
                    acc[mt] = __builtin_amdgcn_mfma_f32_16x16x32_bf16(a[mt][1], b1, acc[mt], 0, 0, 0);
                    acc[mt] = __builtin_amdgcn_mfma_f32_16x16x32_bf16(a[mt][2], b2, acc[mt], 0, 0, 0);
                    acc[mt] = __builtin_amdgcn_mfma_f32_16x16x32_bf16(a[mt][3], b3, acc[mt], 0, 0, 0);
                }
                // restage nt+3 into buffer s (its ds_reads retired by the in-asm lgkmcnt(0));
                // wrap keeps the vmcnt count uniform; tail restages are harmless
                {
                    int ntn = (nt + 3) & 63;
#pragma unroll
                    for (int kf = 0; kf < 4; ++kf)
                        gl_lds16(W4p + (size_t)((ntn * 4 + kf) * 512) + lane * 8,
                                 h3 + s * 2048 + kf * 512);
                }
                s = (s == 2) ? 0 : s + 1;
                float m = fmaxf(fmaxf(fmaxf(acc[0][0], acc[0][1]), fmaxf(acc[0][2], acc[0][3])),
                                fmaxf(fmaxf(acc[1][0], acc[1][1]), fmaxf(acc[1][2], acc[1][3])));
                m = fmaxf(m, fmaxf(fmaxf(fmaxf(acc[2][0], acc[2][1]), fmaxf(acc[2][2], acc[2][3])),
                                   fmaxf(fmaxf(acc[3][0], acc[3][1]), fmaxf(acc[3][2], acc[3][3]))));
                m8[i8] = m;
            }
            // 8 independent 2-shfl chains, results parked in per-wave LDS (no VMEM stores in loop)
#pragma unroll
            for (int qq = 0; qq < 8; ++qq) {
                float v = m8[qq];
                v = fmaxf(v, __shfl_xor(v, 16));
                v = fmaxf(v, __shfl_xor(v, 32));
                m8[qq] = v;
            }
            if (lane < 16) {
#pragma unroll
                for (int qq = 0; qq < 8; ++qq) tmlds[(g8 * 8 + qq) * 16 + lane] = m8[qq];
            }
        }
        // single drain, then coalesced LDS -> global copy of the tile's 1024 col-maxima
        asm volatile("s_waitcnt vmcnt(0) lgkmcnt(0)" ::: "memory");
        float* tm = tilemax + (size_t)wave * 1024;
#pragma unroll
        for (int t = 0; t < 4; ++t) {
            f32x4 v = *reinterpret_cast<const f32x4*>(tmlds + t * 256 + lane * 4);
            *reinterpret_cast<f32x4*>(tm + t * 256 + lane * 4) = v;
        }
        return;
    }

    // ---- slow path (graph-boundary / tail tiles, ~3% of waves): direct global B reads ----
    int gl = -1;
    unsigned long long smask = 0;
    int grow[16];
    {
        long long pl = p0 + lane;
        gl = (pl < Ntot) ? batch[pl] : -1;
        int gprev = __shfl_up(gl, 1);
        bool is_start = (lane == 0) || (gl != gprev);
        smask = __ballot(is_start);
#pragma unroll
        for (int m = 0; m < 4; ++m)
#pragma unroll
            for (int r = 0; r < 4; ++r) {
                int rw = m * 16 + (lane >> 4) * 4 + r;
                grow[m * 4 + r] = __shfl(gl, rw);
            }
    }

    for (int nt = 0; nt < 64; ++nt) {
        bf16x8 bq[4];
#pragma unroll
        for (int kf = 0; kf < 4; ++kf)
            bq[kf] = *reinterpret_cast<const bf16x8*>(W4p + (size_t)((nt * 4 + kf) * 64 + lane) * 8);
        f32x4 acc[4];
#pragma unroll
        for (int m = 0; m < 4; ++m) acc[m] = (f32x4){0.f, 0.f, 0.f, 0.f};
#pragma unroll
        for (int kf = 0; kf < 4; ++kf)
#pragma unroll
            for (int m = 0; m < 4; ++m)
                acc[m] = __builtin_amdgcn_mfma_f32_16x16x32_bf16(a[m][kf], bq[kf], acc[m], 0, 0, 0);

        int col = nt * 16 + (lane & 15);
        float bias = b4[col];
        unsigned long long tmp = smask;
        while (tmp) {
            int ls = __builtin_ctzll(tmp); tmp &= tmp - 1;
            int gs = __shfl(gl, ls);
            float m = -INFINITY;
#pragma unroll
            for (int mm = 0; mm < 4; ++mm)
#pragma unroll
                for (int r = 0; r < 4; ++r)
                    if (grow[mm * 4 + r] == gs) m = fmaxf(m, acc[mm][r]);
            m = fmaxf(m, __shfl_xor(m, 16));
            m = fmaxf(m, __shfl_xor(m, 32));
            if (gs >= 0 && lane < 16 && m > -INFINITY)
                atomicMax(&out[gs * 1024 + col], encf(m + bias));
        }
    }
}

// ---- per-graph fold of tilemax; on the final chunk also merges out-decode (one owner per cell) ----
__global__ __launch_bounds__(256) void reduce_chunk(const float* __restrict__ tilemax,
                                                    const int* __restrict__ gtile,
                                                    const int* __restrict__ batch,
                                                    const float* __restrict__ b4,
                                                    unsigned int* __restrict__ out,
                                                    long long base, long long npts, long long N,
                                                    int finalize) {
    int g = blockIdx.x >> 2;
    int col = (blockIdx.x & 3) * 256 + threadIdx.x;
    __shared__ int sh[2];
    if (threadIdx.x == 0) {
        long long lo = lbound(batch, N, g);
        long long hi = lbound(batch, N, g + 1);
        long long e = base + npts;
        if (lo < base) lo = base;
        if (hi > e) hi = e;
        sh[0] = (int)(lo - base);
        sh[1] = (int)(hi - base);
    }
    __syncthreads();
    int lo = sh[0], hi = sh[1];
    if (!finalize && lo >= hi) return;
    float m = -INFINITY;
    if (lo < hi) {
        int t0 = lo >> 6, t1 = (hi - 1) >> 6;
        for (int t = t0; t <= t1; ++t)
            if (gtile[t] == g) m = fmaxf(m, tilemax[(size_t)t * 1024 + col]);
    }
    int idx = g * 1024 + col;
    if (finalize) {
        // this thread exclusively owns (g,col): non-atomic combine + decode to float bits
        float cur = decf(out[idx]);
        if (m > -INFINITY) cur = fmaxf(cur, m + b4[col]);
        out[idx] = __float_as_uint(cur);
    } else {
        if (m > -INFINITY) atomicMax(&out[idx], encf(m + b4[col]));
    }
}

extern "C" void kernel_launch(void* const* d_in, const int* in_sizes, int n_in,
                              void* d_out, int out_size, void* d_ws, size_t ws_size,
                              hipStream_t stream) {
    const float* x   = (const float*)d_in[0];
    const int* batch = (const int*)d_in[1];
    const float* W1  = (const float*)d_in[2];
    const float* b1  = (const float*)d_in[3];
    const float* g1  = (const float*)d_in[4];
    const float* be1 = (const float*)d_in[5];
    const float* m1  = (const float*)d_in[6];
    const float* v1  = (const float*)d_in[7];
    const float* W2  = (const float*)d_in[8];
    const float* b2  = (const float*)d_in[9];
    const float* W3  = (const float*)d_in[10];
    const float* b3  = (const float*)d_in[11];
    const float* g3  = (const float*)d_in[12];
    const float* be3 = (const float*)d_in[13];
    const float* m3  = (const float*)d_in[14];
    const float* v3  = (const float*)d_in[15];
    const float* W4  = (const float*)d_in[16];
    const float* b4  = (const float*)d_in[17];

    long long N = in_sizes[1];

    char* ws = (char*)d_ws;
    unsigned short* W4p   = (unsigned short*)(ws + 0);       // 262144 B
    unsigned short* W23ph = (unsigned short*)(ws + 262144);  // 16384 B
    unsigned short* W23pl = (unsigned short*)(ws + 278528);  // 16384 B
    float* W1c = (float*)(ws + 294912);                      // 1024 B
    float* b23 = (float*)(ws + 295936);                      // 512 B

    fold_kernel<<<512, 256, 0, stream>>>(W1, b1, g1, be1, m1, v1, W2, b2, W3, b3, g3, be3, m3, v3,
                                         W4, W4p, W23ph, W23pl, W1c, b23,
                                         (unsigned int*)d_out, out_size);

    // per-tile footprint: tilemax 4096 B + gtile 4 B
    const size_t ofs = 1 << 20;
    size_t avail = (ws_size > ofs) ? ws_size - ofs : 0;
    long long Tcap = (long long)(avail / 4104);
    Tcap &= ~3LL;
    if (Tcap < 4) Tcap = 4;
    long long ntiles_tot = (N + 63) / 64;
    long long ntcap = (ntiles_tot + 3) & ~3LL;
    if (Tcap > ntcap) Tcap = ntcap;

    float* tilemax = (float*)(ws + ofs);
    int* gtile = (int*)(ws + ofs + (size_t)Tcap * 4096);
    long long chunk = Tcap * 64;

    for (long long base = 0; base < N; base += chunk) {
        long long npts = N - base; if (npts > chunk) npts = chunk;
        int ntiles = (int)((npts + 63) / 64);
        int blocks = (ntiles + 1) / 2;
        fused_kernel<<<blocks, 128, 0, stream>>>(x, W1c, W23ph, W23pl, b23, W4p, b4, batch,
                                                 (unsigned int*)d_out, tilemax, gtile,
                                                 base, ntiles, N);
        int finalize = (base + chunk >= N) ? 1 : 0;
        reduce_chunk<<<1024, 256, 0, stream>>>(tilemax, gtile, batch, b4, (unsigned int*)d_out,
                                               base, npts, N, finalize);
    }
}

// Round 17
// 210.678 us; speedup vs baseline: 1.1793x; 1.1793x over previous
//
#include <hip/hip_runtime.h>
#include <hip/hip_bf16.h>
#include <cstdint>

typedef __attribute__((ext_vector_type(8))) short bf16x8;
typedef __attribute__((ext_vector_type(4))) float f32x4;

#define BN_EPS 1e-5f

__device__ __forceinline__ unsigned short f2bf(float f) {
    unsigned int u = __float_as_uint(f);
    unsigned int r = (u + 0x7FFFu + ((u >> 16) & 1u)) >> 16;
    return (unsigned short)r;
}
__device__ __forceinline__ float bf2f(unsigned short h) {
    return __uint_as_float(((unsigned int)h) << 16);
}
// monotone float -> uint map (order-preserving), for atomicMax-based float max
__device__ __forceinline__ unsigned int encf(float f) {
    unsigned int u = __float_as_uint(f);
    return (u & 0x80000000u) ? ~u : (u | 0x80000000u);
}
__device__ __forceinline__ float decf(unsigned int e) {
    return __uint_as_float((e & 0x80000000u) ? (e & 0x7FFFFFFFu) : ~e);
}

__device__ __forceinline__ long long lbound(const int* __restrict__ b, long long n, int key) {
    long long lo = 0, hi = n;
    while (lo < hi) { long long mid = (lo + hi) >> 1; if (b[mid] < key) lo = mid + 1; else hi = mid; }
    return lo;
}

__device__ __forceinline__ void gl_lds16(const unsigned short* g, unsigned short* l) {
    __builtin_amdgcn_global_load_lds((const __attribute__((address_space(1))) unsigned int*)g,
                                     (__attribute__((address_space(3))) unsigned int*)l,
                                     16, 0, 0);
}

// ---- fold: BN-fold, W1 interleave, W23 -> bf16 hi/lo B-frags, W4 -> bf16 B-frags, out init ----
__global__ void fold_kernel(const float* __restrict__ W1, const float* __restrict__ b1,
                            const float* __restrict__ g1, const float* __restrict__ be1,
                            const float* __restrict__ m1, const float* __restrict__ v1,
                            const float* __restrict__ W2, const float* __restrict__ b2,
                            const float* __restrict__ W3, const float* __restrict__ b3,
                            const float* __restrict__ g3, const float* __restrict__ be3,
                            const float* __restrict__ m3, const float* __restrict__ v3,
                            const float* __restrict__ W4,
                            unsigned short* __restrict__ W4p,
                            unsigned short* __restrict__ W23ph, unsigned short* __restrict__ W23pl,
                            float* __restrict__ W1c, float* __restrict__ b23,
                            unsigned int* __restrict__ out, int out_size) {
    int tid = blockIdx.x * blockDim.x + threadIdx.x; // 131072 threads
    if (tid < 131072) {
        // W4p flat = ((nt*4+kf)*64 + lane)*8 + j ; element = W4[k][col]
        int j = tid & 7, lane = (tid >> 3) & 63, kf = (tid >> 9) & 3, nt = tid >> 11;
        int col = nt * 16 + (lane & 15);
        int k = kf * 32 + (lane >> 4) * 8 + j;
        W4p[tid] = f2bf(W4[k * 1024 + col]);
    }
    // out init to encf(-inf)
    if (tid < out_size) out[tid] = 0x007FFFFFu;
    if (tid + 131072 < out_size) out[tid + 131072] = 0x007FFFFFu;
    if (tid < 8192) { // W23 (incl. s3) -> B-frag hi/lo: flat = ((nn*2+kf)*64+lane)*8+j
        int j = tid & 7, lane = (tid >> 3) & 63, kf = (tid >> 9) & 1, nn = tid >> 10;
        int col = nn * 16 + (lane & 15);
        int k = kf * 32 + (lane >> 4) * 8 + j;
        float s3 = g3[col] / sqrtf(v3[col] + BN_EPS);
        float acc = 0.f;
        for (int o = 0; o < 64; ++o) acc += W2[k * 64 + o] * W3[o * 128 + col];
        float w = acc * s3;
        unsigned short hi = f2bf(w);
        W23ph[tid] = hi;
        W23pl[tid] = f2bf(w - bf2f(hi));
    }
    if (tid < 128) { // b23[j] = (sum_o b2[o]W3[o][j] + b3[j] - m3[j])*s3[j] + be3[j]
        float s3 = g3[tid] / sqrtf(v3[tid] + BN_EPS);
        float acc = b3[tid] - m3[tid];
        for (int o = 0; o < 64; ++o) acc += b2[o] * W3[o * 128 + tid];
        b23[tid] = acc * s3 + be3[tid];
    }
    if (tid < 256) { // W1c[o][c] = {W1 rows * s1, folded bias}
        int o = tid >> 2, c = tid & 3;
        float s1 = g1[o] / sqrtf(v1[o] + BN_EPS);
        W1c[tid] = (c < 3) ? W1[c * 64 + o] * s1 : (b1[o] - m1[o]) * s1 + be1[o];
    }
}

// ---- fused: 4 waves/block; block-SHARED B-ring (3x4KB), counted vmcnt + raw s_barrier ----
__global__ __launch_bounds__(256, 3) void fused_kernel(const float* __restrict__ x,
                                                       const float* __restrict__ W1c,
                                                       const unsigned short* __restrict__ W23ph,
                                                       const unsigned short* __restrict__ W23pl,
                                                       const float* __restrict__ b23,
                                                       const unsigned short* __restrict__ W4p,
                                                       const float* __restrict__ b4,
                                                       const int* __restrict__ batch,
                                                       unsigned int* __restrict__ out,
                                                       float* __restrict__ tilemax,
                                                       int* __restrict__ gtile,
                                                       long long pbase, int ntiles, long long Ntot) {
    // 4 x 4608-short h3 slices (stride-72 MLP tiles) + shared ring 3 x 2048 shorts = 49152 B
    __shared__ unsigned short ldsall[24576];
    int wv = threadIdx.x >> 6;
    int lane = threadIdx.x & 63;
    int wave = blockIdx.x * 4 + wv;
    bool active = wave < ntiles;          // NO early return: all waves run the barrier skeleton
    unsigned short* h3 = ldsall + wv * 4608;
    unsigned short* ring = ldsall + 18432;
    int q = lane >> 4, r16 = lane & 15;
    long long p0 = pbase + (long long)wave * 64;

    // ---- layer 1 (3->64): lane computes h1[16mt+r16][32kf+8q+j] = its layer-2 A-frag elements ----
    float xv[4][3];
    bool valid[4];
#pragma unroll
    for (int mt = 0; mt < 4; ++mt) {
        long long p = p0 + mt * 16 + r16;
        if (active && p < Ntot) {
            xv[mt][0] = x[p * 3 + 0]; xv[mt][1] = x[p * 3 + 1]; xv[mt][2] = x[p * 3 + 2];
            valid[mt] = true;
        } else {
            xv[mt][0] = xv[mt][1] = xv[mt][2] = 0.f; valid[mt] = false;
        }
    }
    bf16x8 a2[4][2];
#pragma unroll
    for (int kf = 0; kf < 2; ++kf)
#pragma unroll
        for (int j = 0; j < 8; ++j) {
            int f = kf * 32 + q * 8 + j;
            float4 w = *reinterpret_cast<const float4*>(W1c + f * 4);
#pragma unroll
            for (int mt = 0; mt < 4; ++mt) {
                float v = fmaf(xv[mt][0], w.x, fmaf(xv[mt][1], w.y, fmaf(xv[mt][2], w.z, w.w)));
                v = valid[mt] ? fmaxf(v, 0.f) : 0.f;
                a2[mt][kf][j] = (short)f2bf(v);
            }
        }

    // ---- layer 2+3 (64->128) via MFMA in two halves; each half: LDS round-trip -> A-frags ----
    bf16x8 a[4][4];
#pragma unroll
    for (int half = 0; half < 2; ++half) {
#pragma unroll
        for (int n = 0; n < 4; ++n) {
            int nn = half * 4 + n;
            f32x4 acc2[4];
#pragma unroll
            for (int mt = 0; mt < 4; ++mt) acc2[mt] = (f32x4){0.f, 0.f, 0.f, 0.f};
#pragma unroll
            for (int kf = 0; kf < 2; ++kf) {
                bf16x8 bh = *reinterpret_cast<const bf16x8*>(W23ph + (size_t)((nn * 2 + kf) * 64 + lane) * 8);
                bf16x8 bl = *reinterpret_cast<const bf16x8*>(W23pl + (size_t)((nn * 2 + kf) * 64 + lane) * 8);
#pragma unroll
                for (int mt = 0; mt < 4; ++mt) {
                    acc2[mt] = __builtin_amdgcn_mfma_f32_16x16x32_bf16(a2[mt][kf], bh, acc2[mt], 0, 0, 0);
                    acc2[mt] = __builtin_amdgcn_mfma_f32_16x16x32_bf16(a2[mt][kf], bl, acc2[mt], 0, 0, 0);
                }
            }
            int col = nn * 16 + r16;
            float bias = b23[col];
#pragma unroll
            for (int mt = 0; mt < 4; ++mt)
#pragma unroll
                for (int r = 0; r < 4; ++r) {
                    int row = mt * 16 + q * 4 + r;   // C-layout: row=(lane>>4)*4+reg
                    float v = fmaxf(acc2[mt][r] + bias, 0.f);
                    h3[row * 72 + n * 16 + r16] = f2bf(v);
                }
        }
        asm volatile("s_waitcnt lgkmcnt(0)" ::: "memory");
#pragma unroll
        for (int mt = 0; mt < 4; ++mt)
#pragma unroll
            for (int kfl = 0; kfl < 2; ++kfl)
                a[mt][half * 2 + kfl] =
                    *reinterpret_cast<const bf16x8*>(h3 + (16 * mt + r16) * 72 + kfl * 32 + q * 8);
        asm volatile("s_waitcnt lgkmcnt(0)" ::: "memory");
    }

    // ---- tile graph info (inactive waves: fast=false, smask=0 -> zero epilogue work) ----
    bool fast = false;
    int gl = -1;
    unsigned long long smask = 0;
    if (active) {
        long long plast = p0 + 63; if (plast > Ntot - 1) plast = Ntot - 1;
        int gfirst = batch[(p0 < Ntot) ? p0 : (Ntot - 1)];
        int glast = batch[plast];
        fast = (gfirst == glast) && (p0 + 63 < Ntot);
        if (lane == 0) gtile[wave] = fast ? gfirst : -1;
        if (!fast) {
            long long pl = p0 + lane;
            gl = (pl < Ntot) ? batch[pl] : -1;
            int gprev = __shfl_up(gl, 1);
            smask = __ballot((lane == 0) || (gl != gprev));
        }
    }
    int grow[16];
    if (active && !fast) {
#pragma unroll
        for (int m = 0; m < 4; ++m)
#pragma unroll
            for (int r = 0; r < 4; ++r)
                grow[m * 4 + r] = __shfl(gl, m * 16 + (lane >> 4) * 4 + r);
    }

    float* tm = tilemax + (size_t)wave * 1024;

    // ---- shared B-ring prologue: wave wv stages kf=wv quarter of buffers 0,1,2 ----
#pragma unroll
    for (int t = 0; t < 3; ++t)
        gl_lds16(W4p + (size_t)((t * 4 + wv) * 512) + lane * 8,
                 ring + t * 2048 + wv * 512);
    unsigned ringb = (unsigned)(size_t)(__attribute__((address_space(3))) unsigned short*)ring;
    unsigned laddr = ringb + (unsigned)lane * 16u;

    int s = 0;
    for (int g8 = 0; g8 < 8; ++g8) {
        float m8[8];
#pragma unroll
        for (int i8 = 0; i8 < 8; ++i8) {
            int nt = g8 * 8 + i8;
            // counted wait: own stage of buffer s retired. After a g8-epilogue (8 stores newer
            // than all stages) the first 3 iterations need vmcnt(10); first g8 has no stores.
            if (i8 >= 3) {
                asm volatile("s_waitcnt vmcnt(2)" ::: "memory");
            } else if (g8 == 0) {
                asm volatile("s_waitcnt vmcnt(2)" ::: "memory");
            } else {
                asm volatile("s_waitcnt vmcnt(10)" ::: "memory");
            }
            __builtin_amdgcn_s_barrier();     // all 4 waves' quarters of buffer s complete
            unsigned ad = laddr + (unsigned)s * 4096u;
            bf16x8 b0, b1, b2, b3;
            asm volatile("ds_read_b128 %0, %4 offset:0\n\t"
                         "ds_read_b128 %1, %4 offset:1024\n\t"
                         "ds_read_b128 %2, %4 offset:2048\n\t"
                         "ds_read_b128 %3, %4 offset:3072\n\t"
                         "s_waitcnt lgkmcnt(0)"
                         : "=&v"(b0), "=&v"(b1), "=&v"(b2), "=&v"(b3)
                         : "v"(ad) : "memory");
            __builtin_amdgcn_s_barrier();     // all waves' reads of buffer s retired
            {   // restage buffer s <- nt+3 (wrap keeps counts uniform; tail restages harmless)
                int ntn = (nt + 3) & 63;
                gl_lds16(W4p + (size_t)((ntn * 4 + wv) * 512) + lane * 8,
                         ring + s * 2048 + wv * 512);
            }
            s = (s == 2) ? 0 : s + 1;
            f32x4 acc[4];
#pragma unroll
            for (int mt = 0; mt < 4; ++mt) acc[mt] = (f32x4){0.f, 0.f, 0.f, 0.f};
#pragma unroll
            for (int mt = 0; mt < 4; ++mt) {
                acc[mt] = __builtin_amdgcn_mfma_f32_16x16x32_bf16(a[mt][0], b0, acc[mt], 0, 0, 0);
                acc[mt] = __builtin_amdgcn_mfma_f32_16x16x32_bf16(a[mt][1], b1, acc[mt], 0, 0, 0);
                acc[mt] = __builtin_amdgcn_mfma_f32_16x16x32_bf16(a[mt][2], b2, acc[mt], 0, 0, 0);
                acc[mt] = __builtin_amdgcn_mfma_f32_16x16x32_bf16(a[mt][3], b3, acc[mt], 0, 0, 0);
            }
            if (fast) {
                float m = fmaxf(fmaxf(fmaxf(acc[0][0], acc[0][1]), fmaxf(acc[0][2], acc[0][3])),
                                fmaxf(fmaxf(acc[1][0], acc[1][1]), fmaxf(acc[1][2], acc[1][3])));
                m = fmaxf(m, fmaxf(fmaxf(fmaxf(acc[2][0], acc[2][1]), fmaxf(acc[2][2], acc[2][3])),
                                   fmaxf(fmaxf(acc[3][0], acc[3][1]), fmaxf(acc[3][2], acc[3][3]))));
                m8[i8] = m;
            } else if (active) {
                int col = nt * 16 + (lane & 15);
                float bias = b4[col];
                unsigned long long tmp = smask;
                while (tmp) {
                    int ls = __builtin_ctzll(tmp); tmp &= tmp - 1;
                    int gs = __shfl(gl, ls);
                    float m = -INFINITY;
#pragma unroll
                    for (int mm = 0; mm < 4; ++mm)
#pragma unroll
                        for (int r = 0; r < 4; ++r)
                            if (grow[mm * 4 + r] == gs) m = fmaxf(m, acc[mm][r]);
                    m = fmaxf(m, __shfl_xor(m, 16));
                    m = fmaxf(m, __shfl_xor(m, 32));
                    if (gs >= 0 && lane < 16 && m > -INFINITY)
                        atomicMax(&out[gs * 1024 + col], encf(m + bias));
                }
            }
        }
        if (fast) {
            // 8 independent 2-shfl chains, then 8 stores (newest VMEM ops; accounted in vmcnt)
#pragma unroll
            for (int qq = 0; qq < 8; ++qq) {
                float v = m8[qq];
                v = fmaxf(v, __shfl_xor(v, 16));
                v = fmaxf(v, __shfl_xor(v, 32));
                m8[qq] = v;
            }
            if (lane < 16) {
#pragma unroll
                for (int qq = 0; qq < 8; ++qq) tm[(g8 * 8 + qq) * 16 + lane] = m8[qq];
            }
        }
    }
}

// ---- per-graph fold of tilemax; on the final chunk also merges out-decode (one owner per cell) ----
__global__ __launch_bounds__(256) void reduce_chunk(const float* __restrict__ tilemax,
                                                    const int* __restrict__ gtile,
                                                    const int* __restrict__ batch,
                                                    const float* __restrict__ b4,
                                                    unsigned int* __restrict__ out,
                                                    long long base, long long npts, long long N,
                                                    int finalize) {
    int g = blockIdx.x >> 2;
    int col = (blockIdx.x & 3) * 256 + threadIdx.x;
    __shared__ int sh[2];
    if (threadIdx.x == 0) {
        long long lo = lbound(batch, N, g);
        long long hi = lbound(batch, N, g + 1);
        long long e = base + npts;
        if (lo < base) lo = base;
        if (hi > e) hi = e;
        sh[0] = (int)(lo - base);
        sh[1] = (int)(hi - base);
    }
    __syncthreads();
    int lo = sh[0], hi = sh[1];
    if (!finalize && lo >= hi) return;
    float m = -INFINITY;
    if (lo < hi) {
        int t0 = lo >> 6, t1 = (hi - 1) >> 6;
        for (int t = t0; t <= t1; ++t)
            if (gtile[t] == g) m = fmaxf(m, tilemax[(size_t)t * 1024 + col]);
    }
    int idx = g * 1024 + col;
    if (finalize) {
        // this thread exclusively owns (g,col): non-atomic combine + decode to float bits
        float cur = decf(out[idx]);
        if (m > -INFINITY) cur = fmaxf(cur, m + b4[col]);
        out[idx] = __float_as_uint(cur);
    } else {
        if (m > -INFINITY) atomicMax(&out[idx], encf(m + b4[col]));
    }
}

extern "C" void kernel_launch(void* const* d_in, const int* in_sizes, int n_in,
                              void* d_out, int out_size, void* d_ws, size_t ws_size,
                              hipStream_t stream) {
    const float* x   = (const float*)d_in[0];
    const int* batch = (const int*)d_in[1];
    const float* W1  = (const float*)d_in[2];
    const float* b1  = (const float*)d_in[3];
    const float* g1  = (const float*)d_in[4];
    const float* be1 = (const float*)d_in[5];
    const float* m1  = (const float*)d_in[6];
    const float* v1  = (const float*)d_in[7];
    const float* W2  = (const float*)d_in[8];
    const float* b2  = (const float*)d_in[9];
    const float* W3  = (const float*)d_in[10];
    const float* b3  = (const float*)d_in[11];
    const float* g3  = (const float*)d_in[12];
    const float* be3 = (const float*)d_in[13];
    const float* m3  = (const float*)d_in[14];
    const float* v3  = (const float*)d_in[15];
    const float* W4  = (const float*)d_in[16];
    const float* b4  = (const float*)d_in[17];

    long long N = in_sizes[1];

    char* ws = (char*)d_ws;
    unsigned short* W4p   = (unsigned short*)(ws + 0);       // 262144 B
    unsigned short* W23ph = (unsigned short*)(ws + 262144);  // 16384 B
    unsigned short* W23pl = (unsigned short*)(ws + 278528);  // 16384 B
    float* W1c = (float*)(ws + 294912);                      // 1024 B
    float* b23 = (float*)(ws + 295936);                      // 512 B

    fold_kernel<<<512, 256, 0, stream>>>(W1, b1, g1, be1, m1, v1, W2, b2, W3, b3, g3, be3, m3, v3,
                                         W4, W4p, W23ph, W23pl, W1c, b23,
                                         (unsigned int*)d_out, out_size);

    // per-tile footprint: tilemax 4096 B + gtile 4 B
    const size_t ofs = 1 << 20;
    size_t avail = (ws_size > ofs) ? ws_size - ofs : 0;
    long long Tcap = (long long)(avail / 4104);
    Tcap &= ~3LL;
    if (Tcap < 4) Tcap = 4;
    long long ntiles_tot = (N + 63) / 64;
    long long ntcap = (ntiles_tot + 3) & ~3LL;
    if (Tcap > ntcap) Tcap = ntcap;

    float* tilemax = (float*)(ws + ofs);
    int* gtile = (int*)(ws + ofs + (size_t)Tcap * 4096);
    long long chunk = Tcap * 64;

    for (long long base = 0; base < N; base += chunk) {
        long long npts = N - base; if (npts > chunk) npts = chunk;
        int ntiles = (int)((npts + 63) / 64);
        int blocks = (ntiles + 3) / 4;
        fused_kernel<<<blocks, 256, 0, stream>>>(x, W1c, W23ph, W23pl, b23, W4p, b4, batch,
                                                 (unsigned int*)d_out, tilemax, gtile,
                                                 base, ntiles, N);
        int finalize = (base + chunk >= N) ? 1 : 0;
        reduce_chunk<<<1024, 256, 0, stream>>>(tilemax, gtile, batch, b4, (unsigned int*)d_out,
                                               base, npts, N, finalize);
    }
}

// Round 18
// 202.385 us; speedup vs baseline: 1.2276x; 1.0410x over previous
//
#include <hip/hip_runtime.h>
#include <hip/hip_bf16.h>
#include <cstdint>

typedef __attribute__((ext_vector_type(8))) short bf16x8;
typedef __attribute__((ext_vector_type(4))) float f32x4;

#define BN_EPS 1e-5f

__device__ __forceinline__ unsigned short f2bf(float f) {
    unsigned int u = __float_as_uint(f);
    unsigned int r = (u + 0x7FFFu + ((u >> 16) & 1u)) >> 16;
    return (unsigned short)r;
}
__device__ __forceinline__ float bf2f(unsigned short h) {
    return __uint_as_float(((unsigned int)h) << 16);
}
// monotone float -> uint map (order-preserving), for atomicMax-based float max
__device__ __forceinline__ unsigned int encf(float f) {
    unsigned int u = __float_as_uint(f);
    return (u & 0x80000000u) ? ~u : (u | 0x80000000u);
}
__device__ __forceinline__ float decf(unsigned int e) {
    return __uint_as_float((e & 0x80000000u) ? (e & 0x7FFFFFFFu) : ~e);
}

__device__ __forceinline__ long long lbound(const int* __restrict__ b, long long n, int key) {
    long long lo = 0, hi = n;
    while (lo < hi) { long long mid = (lo + hi) >> 1; if (b[mid] < key) lo = mid + 1; else hi = mid; }
    return lo;
}

// ---- fold: BN-fold, W1 interleave, W23 -> bf16 hi/lo B-frags, W4 -> bf16 B-frags, out init ----
__global__ void fold_kernel(const float* __restrict__ W1, const float* __restrict__ b1,
                            const float* __restrict__ g1, const float* __restrict__ be1,
                            const float* __restrict__ m1, const float* __restrict__ v1,
                            const float* __restrict__ W2, const float* __restrict__ b2,
                            const float* __restrict__ W3, const float* __restrict__ b3,
                            const float* __restrict__ g3, const float* __restrict__ be3,
                            const float* __restrict__ m3, const float* __restrict__ v3,
                            const float* __restrict__ W4,
                            unsigned short* __restrict__ W4p,
                            unsigned short* __restrict__ W23ph, unsigned short* __restrict__ W23pl,
                            float* __restrict__ W1c, float* __restrict__ b23,
                            unsigned int* __restrict__ out, int out_size) {
    int tid = blockIdx.x * blockDim.x + threadIdx.x; // 131072 threads
    if (tid < 131072) {
        // W4p flat = ((nt*4+kf)*64 + lane)*8 + j ; element = W4[k][col]
        int j = tid & 7, lane = (tid >> 3) & 63, kf = (tid >> 9) & 3, nt = tid >> 11;
        int col = nt * 16 + (lane & 15);
        int k = kf * 32 + (lane >> 4) * 8 + j;
        W4p[tid] = f2bf(W4[k * 1024 + col]);
    }
    // out init to encf(-inf)
    if (tid < out_size) out[tid] = 0x007FFFFFu;
    if (tid + 131072 < out_size) out[tid + 131072] = 0x007FFFFFu;
    if (tid < 8192) { // W23 (incl. s3) -> B-frag hi/lo: flat = ((nn*2+kf)*64+lane)*8+j
        int j = tid & 7, lane = (tid >> 3) & 63, kf = (tid >> 9) & 1, nn = tid >> 10;
        int col = nn * 16 + (lane & 15);
        int k = kf * 32 + (lane >> 4) * 8 + j;
        float s3 = g3[col] / sqrtf(v3[col] + BN_EPS);
        float acc = 0.f;
        for (int o = 0; o < 64; ++o) acc += W2[k * 64 + o] * W3[o * 128 + col];
        float w = acc * s3;
        unsigned short hi = f2bf(w);
        W23ph[tid] = hi;
        W23pl[tid] = f2bf(w - bf2f(hi));
    }
    if (tid < 128) { // b23[j] = (sum_o b2[o]W3[o][j] + b3[j] - m3[j])*s3[j] + be3[j]
        float s3 = g3[tid] / sqrtf(v3[tid] + BN_EPS);
        float acc = b3[tid] - m3[tid];
        for (int o = 0; o < 64; ++o) acc += b2[o] * W3[o * 128 + tid];
        b23[tid] = acc * s3 + be3[tid];
    }
    if (tid < 256) { // W1c[o][c] = {W1 rows * s1, folded bias}
        int o = tid >> 2, c = tid & 3;
        float s1 = g1[o] / sqrtf(v1[o] + BN_EPS);
        W1c[tid] = (c < 3) ? W1[c * 64 + o] * s1 : (b1[o] - m1[o]) * s1 + be1[o];
    }
}

// ---------------- fused: layer1 VALU -> layer2 MFMA (half-split LDS) -> layer4 MFMA pipelined ----
// (exact R7 body: stride-72 LDS, inline MLP, hoisted slow-path grow, depth-1 ping-pong prefetch)
__global__ __launch_bounds__(64, 4) void fused_kernel(const float* __restrict__ x,
                                                      const float* __restrict__ W1c,
                                                      const unsigned short* __restrict__ W23ph,
                                                      const unsigned short* __restrict__ W23pl,
                                                      const float* __restrict__ b23,
                                                      const unsigned short* __restrict__ W4p,
                                                      const float* __restrict__ b4,
                                                      const int* __restrict__ batch,
                                                      unsigned int* __restrict__ out,
                                                      float* __restrict__ tilemax,
                                                      int* __restrict__ gtile,
                                                      long long pbase, int ntiles, long long Ntot) {
    __shared__ unsigned short h3[64 * 72];   // one 64-feature half, row stride 144 B
    int wave = blockIdx.x;
    if (wave >= ntiles) return;
    int lane = threadIdx.x & 63;
    int q = lane >> 4, r16 = lane & 15;
    long long p0 = pbase + (long long)wave * 64;

    // ---- layer 1 (3->64): lane computes h1[16mt+r16][32kf+8q+j] = its layer-2 A-frag elements ----
    float xv[4][3];
    bool valid[4];
#pragma unroll
    for (int mt = 0; mt < 4; ++mt) {
        long long p = p0 + mt * 16 + r16;
        if (p < Ntot) {
            xv[mt][0] = x[p * 3 + 0]; xv[mt][1] = x[p * 3 + 1]; xv[mt][2] = x[p * 3 + 2];
            valid[mt] = true;
        } else {
            xv[mt][0] = xv[mt][1] = xv[mt][2] = 0.f; valid[mt] = false;
        }
    }
    bf16x8 a2[4][2];
#pragma unroll
    for (int kf = 0; kf < 2; ++kf)
#pragma unroll
        for (int j = 0; j < 8; ++j) {
            int f = kf * 32 + q * 8 + j;
            float4 w = *reinterpret_cast<const float4*>(W1c + f * 4);
#pragma unroll
            for (int mt = 0; mt < 4; ++mt) {
                float v = fmaf(xv[mt][0], w.x, fmaf(xv[mt][1], w.y, fmaf(xv[mt][2], w.z, w.w)));
                v = valid[mt] ? fmaxf(v, 0.f) : 0.f;
                a2[mt][kf][j] = (short)f2bf(v);
            }
        }

    // ---- layer 2+3 (64->128) via MFMA in two halves; each half: LDS round-trip -> A-frags ----
    bf16x8 a[4][4];
#pragma unroll
    for (int half = 0; half < 2; ++half) {
#pragma unroll
        for (int n = 0; n < 4; ++n) {
            int nn = half * 4 + n;
            f32x4 acc2[4];
#pragma unroll
            for (int mt = 0; mt < 4; ++mt) acc2[mt] = (f32x4){0.f, 0.f, 0.f, 0.f};
#pragma unroll
            for (int kf = 0; kf < 2; ++kf) {
                bf16x8 bh = *reinterpret_cast<const bf16x8*>(W23ph + (size_t)((nn * 2 + kf) * 64 + lane) * 8);
                bf16x8 bl = *reinterpret_cast<const bf16x8*>(W23pl + (size_t)((nn * 2 + kf) * 64 + lane) * 8);
#pragma unroll
                for (int mt = 0; mt < 4; ++mt) {
                    acc2[mt] = __builtin_amdgcn_mfma_f32_16x16x32_bf16(a2[mt][kf], bh, acc2[mt], 0, 0, 0);
                    acc2[mt] = __builtin_amdgcn_mfma_f32_16x16x32_bf16(a2[mt][kf], bl, acc2[mt], 0, 0, 0);
                }
            }
            int col = nn * 16 + r16;
            float bias = b23[col];
#pragma unroll
            for (int mt = 0; mt < 4; ++mt)
#pragma unroll
                for (int r = 0; r < 4; ++r) {
                    int row = mt * 16 + q * 4 + r;   // C-layout: row=(lane>>4)*4+reg
                    float v = fmaxf(acc2[mt][r] + bias, 0.f);
                    h3[row * 72 + n * 16 + r16] = f2bf(v);
                }
        }
        asm volatile("s_waitcnt lgkmcnt(0)" ::: "memory");
        // read this half's A-frags: a[mt][half*2+kfl][j] = h3half[16mt+r16][kfl*32+q*8+j]
#pragma unroll
        for (int mt = 0; mt < 4; ++mt)
#pragma unroll
            for (int kfl = 0; kfl < 2; ++kfl)
                a[mt][half * 2 + kfl] =
                    *reinterpret_cast<const bf16x8*>(h3 + (16 * mt + r16) * 72 + kfl * 32 + q * 8);
        asm volatile("s_waitcnt lgkmcnt(0)" ::: "memory");
    }

    long long plast = p0 + 63; if (plast > Ntot - 1) plast = Ntot - 1;
    int gfirst = batch[(p0 < Ntot) ? p0 : (Ntot - 1)];
    int glast = batch[plast];
    bool fast = (gfirst == glast) && (p0 + 63 < Ntot);
    if (lane == 0) gtile[wave] = fast ? gfirst : -1;

    if (fast) {
        float* tm = tilemax + (size_t)wave * 1024;
        const unsigned short* wp = W4p + (size_t)lane * 8;
        bf16x8 Bp[2][4];
#pragma unroll
        for (int kf = 0; kf < 4; ++kf)
            Bp[0][kf] = *reinterpret_cast<const bf16x8*>(wp + (size_t)kf * 512);

        for (int g8 = 0; g8 < 8; ++g8) {
            float m8[8];
#pragma unroll
            for (int i8 = 0; i8 < 8; ++i8) {
                int nt = g8 * 8 + i8;
                const int cur = i8 & 1, nxt = cur ^ 1;
                // prefetch nt+1 (wrap at 63; one wasted prefetch on the last iteration)
                {
                    const unsigned short* wq = wp + (size_t)(((nt + 1) & 63) * 4) * 512;
#pragma unroll
                    for (int kf = 0; kf < 4; ++kf)
                        Bp[nxt][kf] = *reinterpret_cast<const bf16x8*>(wq + (size_t)kf * 512);
                }
                f32x4 acc[4];
#pragma unroll
                for (int mt = 0; mt < 4; ++mt) acc[mt] = (f32x4){0.f, 0.f, 0.f, 0.f};
#pragma unroll
                for (int kf = 0; kf < 4; ++kf)
#pragma unroll
                    for (int mt = 0; mt < 4; ++mt)
                        acc[mt] = __builtin_amdgcn_mfma_f32_16x16x32_bf16(a[mt][kf], Bp[cur][kf], acc[mt], 0, 0, 0);
                float m = fmaxf(fmaxf(fmaxf(acc[0][0], acc[0][1]), fmaxf(acc[0][2], acc[0][3])),
                                fmaxf(fmaxf(acc[1][0], acc[1][1]), fmaxf(acc[1][2], acc[1][3])));
                m = fmaxf(m, fmaxf(fmaxf(fmaxf(acc[2][0], acc[2][1]), fmaxf(acc[2][2], acc[2][3])),
                                   fmaxf(fmaxf(acc[3][0], acc[3][1]), fmaxf(acc[3][2], acc[3][3]))));
                m8[i8] = m;
            }
            // 8 independent 2-shfl chains (DS latency amortized), then 8 stores
#pragma unroll
            for (int qq = 0; qq < 8; ++qq) {
                float v = m8[qq];
                v = fmaxf(v, __shfl_xor(v, 16));
                v = fmaxf(v, __shfl_xor(v, 32));
                m8[qq] = v;
            }
            if (lane < 16) {
#pragma unroll
                for (int qq = 0; qq < 8; ++qq) tm[(g8 * 8 + qq) * 16 + lane] = m8[qq];
            }
        }
        return;
    }

    // ---- slow path (graph-boundary / tail tiles, ~3% of waves) ----
    int gl = -1;
    unsigned long long smask = 0;
    int grow[16];
    {
        long long pl = p0 + lane;
        gl = (pl < Ntot) ? batch[pl] : -1;
        int gprev = __shfl_up(gl, 1);
        bool is_start = (lane == 0) || (gl != gprev);
        smask = __ballot(is_start);
#pragma unroll
        for (int m = 0; m < 4; ++m)
#pragma unroll
            for (int r = 0; r < 4; ++r) {
                int rw = m * 16 + (lane >> 4) * 4 + r;
                grow[m * 4 + r] = __shfl(gl, rw);
            }
    }

    for (int nt = 0; nt < 64; ++nt) {
        bf16x8 bq[4];
#pragma unroll
        for (int kf = 0; kf < 4; ++kf)
            bq[kf] = *reinterpret_cast<const bf16x8*>(W4p + (size_t)((nt * 4 + kf) * 64 + lane) * 8);
        f32x4 acc[4];
#pragma unroll
        for (int m = 0; m < 4; ++m) acc[m] = (f32x4){0.f, 0.f, 0.f, 0.f};
#pragma unroll
        for (int kf = 0; kf < 4; ++kf)
#pragma unroll
            for (int m = 0; m < 4; ++m)
                acc[m] = __builtin_amdgcn_mfma_f32_16x16x32_bf16(a[m][kf], bq[kf], acc[m], 0, 0, 0);

        int col = nt * 16 + (lane & 15);
        float bias = b4[col];
        unsigned long long tmp = smask;
        while (tmp) {
            int ls = __builtin_ctzll(tmp); tmp &= tmp - 1;
            int gs = __shfl(gl, ls);
            float m = -INFINITY;
#pragma unroll
            for (int mm = 0; mm < 4; ++mm)
#pragma unroll
                for (int r = 0; r < 4; ++r)
                    if (grow[mm * 4 + r] == gs) m = fmaxf(m, acc[mm][r]);
            m = fmaxf(m, __shfl_xor(m, 16));
            m = fmaxf(m, __shfl_xor(m, 32));
            if (gs >= 0 && lane < 16 && m > -INFINITY)
                atomicMax(&out[gs * 1024 + col], encf(m + bias));
        }
    }
}

// ---- per-graph fold of tilemax; on the final chunk also merges out-decode (one owner per cell) ----
__global__ __launch_bounds__(256) void reduce_chunk(const float* __restrict__ tilemax,
                                                    const int* __restrict__ gtile,
                                                    const int* __restrict__ batch,
                                                    const float* __restrict__ b4,
                                                    unsigned int* __restrict__ out,
                                                    long long base, long long npts, long long N,
                                                    int finalize) {
    int g = blockIdx.x >> 2;
    int col = (blockIdx.x & 3) * 256 + threadIdx.x;
    __shared__ int sh[2];
    if (threadIdx.x == 0) {
        long long lo = lbound(batch, N, g);
        long long hi = lbound(batch, N, g + 1);
        long long e = base + npts;
        if (lo < base) lo = base;
        if (hi > e) hi = e;
        sh[0] = (int)(lo - base);
        sh[1] = (int)(hi - base);
    }
    __syncthreads();
    int lo = sh[0], hi = sh[1];
    if (!finalize && lo >= hi) return;
    float m = -INFINITY;
    if (lo < hi) {
        int t0 = lo >> 6, t1 = (hi - 1) >> 6;
        for (int t = t0; t <= t1; ++t)
            if (gtile[t] == g) m = fmaxf(m, tilemax[(size_t)t * 1024 + col]);
    }
    int idx = g * 1024 + col;
    if (finalize) {
        // this thread exclusively owns (g,col): non-atomic combine + decode to float bits
        float cur = decf(out[idx]);
        if (m > -INFINITY) cur = fmaxf(cur, m + b4[col]);
        out[idx] = __float_as_uint(cur);
    } else {
        if (m > -INFINITY) atomicMax(&out[idx], encf(m + b4[col]));
    }
}

extern "C" void kernel_launch(void* const* d_in, const int* in_sizes, int n_in,
                              void* d_out, int out_size, void* d_ws, size_t ws_size,
                              hipStream_t stream) {
    const float* x   = (const float*)d_in[0];
    const int* batch = (const int*)d_in[1];
    const float* W1  = (const float*)d_in[2];
    const float* b1  = (const float*)d_in[3];
    const float* g1  = (const float*)d_in[4];
    const float* be1 = (const float*)d_in[5];
    const float* m1  = (const float*)d_in[6];
    const float* v1  = (const float*)d_in[7];
    const float* W2  = (const float*)d_in[8];
    const float* b2  = (const float*)d_in[9];
    const float* W3  = (const float*)d_in[10];
    const float* b3  = (const float*)d_in[11];
    const float* g3  = (const float*)d_in[12];
    const float* be3 = (const float*)d_in[13];
    const float* m3  = (const float*)d_in[14];
    const float* v3  = (const float*)d_in[15];
    const float* W4  = (const float*)d_in[16];
    const float* b4  = (const float*)d_in[17];

    long long N = in_sizes[1];

    char* ws = (char*)d_ws;
    unsigned short* W4p   = (unsigned short*)(ws + 0);       // 262144 B
    unsigned short* W23ph = (unsigned short*)(ws + 262144);  // 16384 B
    unsigned short* W23pl = (unsigned short*)(ws + 278528);  // 16384 B
    float* W1c = (float*)(ws + 294912);                      // 1024 B
    float* b23 = (float*)(ws + 295936);                      // 512 B

    fold_kernel<<<512, 256, 0, stream>>>(W1, b1, g1, be1, m1, v1, W2, b2, W3, b3, g3, be3, m3, v3,
                                         W4, W4p, W23ph, W23pl, W1c, b23,
                                         (unsigned int*)d_out, out_size);

    // per-tile footprint: tilemax 4096 B + gtile 4 B
    const size_t ofs = 1 << 20;
    size_t avail = (ws_size > ofs) ? ws_size - ofs : 0;
    long long Tcap = (long long)(avail / 4104);
    Tcap &= ~3LL;
    if (Tcap < 4) Tcap = 4;
    long long ntiles_tot = (N + 63) / 64;
    long long ntcap = (ntiles_tot + 3) & ~3LL;
    if (Tcap > ntcap) Tcap = ntcap;

    float* tilemax = (float*)(ws + ofs);
    int* gtile = (int*)(ws + ofs + (size_t)Tcap * 4096);
    long long chunk = Tcap * 64;

    for (long long base = 0; base < N; base += chunk) {
        long long npts = N - base; if (npts > chunk) npts = chunk;
        int ntiles = (int)((npts + 63) / 64);
        fused_kernel<<<ntiles, 64, 0, stream>>>(x, W1c, W23ph, W23pl, b23, W4p, b4, batch,
                                                (unsigned int*)d_out, tilemax, gtile,
                                                base, ntiles, N);
        int finalize = (base + chunk >= N) ? 1 : 0;
        reduce_chunk<<<1024, 256, 0, stream>>>(tilemax, gtile, batch, b4, (unsigned int*)d_out,
                                               base, npts, N, finalize);
    }
}